// Round 1
// baseline (2887.463 us; speedup 1.0000x reference)
//
#include <hip/hip_runtime.h>
#include <math.h>

#define NROWS 6272
#define CDIM  768
#define HIDD  3072

#define EPI_BIAS 0
#define EPI_SIG  1
#define EPI_GELU 2
#define EPI_RES  3

#define BM 64
#define BN 64
#define BK 16

// ---------------- LayerNorm: one block (256 thr) per row of 768 ----------------
__global__ __launch_bounds__(256) void ln_kernel(const float* __restrict__ x,
                                                 const float* __restrict__ sc,
                                                 const float* __restrict__ bi,
                                                 float* __restrict__ o) {
    const int row = blockIdx.x;
    const float* xr = x + (size_t)row * CDIM;
    float* orow = o + (size_t)row * CDIM;
    const int t = threadIdx.x;

    float v0 = xr[t], v1 = xr[t + 256], v2 = xr[t + 512];
    float s = v0 + v1 + v2;

    __shared__ float sm[8];
    #pragma unroll
    for (int off = 32; off > 0; off >>= 1) s += __shfl_xor(s, off);
    const int wid = t >> 6, lane = t & 63;
    if (lane == 0) sm[wid] = s;
    __syncthreads();
    const float mu = (sm[0] + sm[1] + sm[2] + sm[3]) * (1.0f / 768.0f);

    const float d0 = v0 - mu, d1 = v1 - mu, d2 = v2 - mu;
    float s2 = d0 * d0 + d1 * d1 + d2 * d2;
    #pragma unroll
    for (int off = 32; off > 0; off >>= 1) s2 += __shfl_xor(s2, off);
    if (lane == 0) sm[4 + wid] = s2;
    __syncthreads();
    const float var = (sm[4] + sm[5] + sm[6] + sm[7]) * (1.0f / 768.0f);
    const float r = rsqrtf(var + 1e-6f);

    orow[t]       = d0 * r * sc[t]       + bi[t];
    orow[t + 256] = d1 * r * sc[t + 256] + bi[t + 256];
    orow[t + 512] = d2 * r * sc[t + 512] + bi[t + 512];
}

// ---------------- Generic fp32 tiled GEMM: out = epi(A @ B + bias) ----------------
// A: M x K row-major (CONCAT: A0|A1 each N x 768 along K, K==1536)
// B: K x Nout row-major. Grid: (Nout/BN, M/BM). 256 threads, 4x4 per thread.
template <int EPI, bool CONCAT>
__global__ __launch_bounds__(256) void gemm_k(const float* __restrict__ A0,
                                              const float* __restrict__ A1,
                                              const float* __restrict__ B,
                                              const float* __restrict__ bias,
                                              const float* __restrict__ gamma,
                                              const float* __restrict__ res,
                                              float* __restrict__ out,
                                              int K, int Nout) {
    __shared__ float As[BK][BM + 4];   // +4 pad keeps float4 rows 16B-aligned, breaks bank stride
    __shared__ float Bs[BK][BN];

    const int t  = threadIdx.x;
    const int tx = t & 15, ty = t >> 4;
    const int m0 = blockIdx.y * BM;
    const int n0 = blockIdx.x * BN;

    // A staging: thread t loads one float4: row am, k-quad akq
    const int am  = t >> 2;
    const int akq = (t & 3) * 4;
    // B staging: thread t loads one float4: k-row bk, col-quad bn4
    const int bk  = t >> 4;
    const int bn4 = (t & 15) * 4;

    float acc[4][4] = {};

    for (int k0 = 0; k0 < K; k0 += BK) {
        const int kg = k0 + akq;
        const float* aptr;
        if (CONCAT) {
            aptr = (kg < 768) ? (A0 + (size_t)(m0 + am) * 768 + kg)
                              : (A1 + (size_t)(m0 + am) * 768 + (kg - 768));
        } else {
            aptr = A0 + (size_t)(m0 + am) * K + kg;
        }
        const float4 av = *(const float4*)aptr;
        const float4 bv = *(const float4*)(B + (size_t)(k0 + bk) * Nout + n0 + bn4);

        __syncthreads();   // previous tile fully consumed
        As[akq + 0][am] = av.x;
        As[akq + 1][am] = av.y;
        As[akq + 2][am] = av.z;
        As[akq + 3][am] = av.w;
        *(float4*)&Bs[bk][bn4] = bv;
        __syncthreads();

        #pragma unroll
        for (int kk = 0; kk < BK; ++kk) {
            const float4 a = *(const float4*)&As[kk][ty * 4];
            const float4 b = *(const float4*)&Bs[kk][tx * 4];
            const float ar[4] = {a.x, a.y, a.z, a.w};
            const float br[4] = {b.x, b.y, b.z, b.w};
            #pragma unroll
            for (int i = 0; i < 4; ++i)
                #pragma unroll
                for (int j = 0; j < 4; ++j)
                    acc[i][j] += ar[i] * br[j];
        }
    }

    const int row0 = m0 + ty * 4;
    const int col0 = n0 + tx * 4;
    #pragma unroll
    for (int i = 0; i < 4; ++i) {
        float4 o;
        float* po = (float*)&o;
        #pragma unroll
        for (int j = 0; j < 4; ++j) {
            float z = acc[i][j] + bias[col0 + j];
            if (EPI == EPI_SIG) {
                z = 1.0f / (1.0f + __expf(-z));
            } else if (EPI == EPI_GELU) {
                const float z3 = z * z * z;
                z = 0.5f * z * (1.0f + tanhf(0.7978845608028654f * (z + 0.044715f * z3)));
            } else if (EPI == EPI_RES) {
                z = res[(size_t)(row0 + i) * Nout + (col0 + j)] + z * gamma[col0 + j];
            }
            po[j] = z;
        }
        *(float4*)&out[(size_t)(row0 + i) * Nout + col0] = o;
    }
}

// ---------------- recurrence helpers ----------------
// t=0 step collapses to hx=u, hy=0 (since hx=hy=0 makes the gate irrelevant)
__global__ __launch_bounds__(256) void init_state(const float* __restrict__ u,
                                                  float* __restrict__ hx,
                                                  float* __restrict__ hy, int n4) {
    const int i = blockIdx.x * blockDim.x + threadIdx.x;
    if (i >= n4) return;
    ((float4*)hx)[i] = ((const float4*)u)[i];
    ((float4*)hy)[i] = make_float4(0.f, 0.f, 0.f, 0.f);
}

__global__ __launch_bounds__(256) void state_update(const float* __restrict__ g,
                                                    const float* __restrict__ u,
                                                    float* __restrict__ hx,
                                                    float* __restrict__ hy,
                                                    const float* __restrict__ ad,
                                                    const float* __restrict__ br, int n4) {
    const int i = blockIdx.x * blockDim.x + threadIdx.x;
    if (i >= n4) return;
    const int cb = i % (CDIM / 4);
    const float4 a4 = ((const float4*)ad)[cb];
    const float4 b4 = ((const float4*)br)[cb];
    const float4 gv = ((const float4*)g)[i];
    const float4 uv = ((const float4*)u)[i];
    const float4 xv = ((const float4*)hx)[i];
    const float4 yv = ((const float4*)hy)[i];
    float4 nx, ny;
    nx.x = gv.x * (a4.x * xv.x - b4.x * yv.x) + uv.x;  ny.x = gv.x * (b4.x * xv.x + a4.x * yv.x);
    nx.y = gv.y * (a4.y * xv.y - b4.y * yv.y) + uv.y;  ny.y = gv.y * (b4.y * xv.y + a4.y * yv.y);
    nx.z = gv.z * (a4.z * xv.z - b4.z * yv.z) + uv.z;  ny.z = gv.z * (b4.z * xv.z + a4.z * yv.z);
    nx.w = gv.w * (a4.w * xv.w - b4.w * yv.w) + uv.w;  ny.w = gv.w * (b4.w * xv.w + a4.w * yv.w);
    ((float4*)hx)[i] = nx;
    ((float4*)hy)[i] = ny;
}

extern "C" void kernel_launch(void* const* d_in, const int* in_sizes, int n_in,
                              void* d_out, int out_size, void* d_ws, size_t ws_size,
                              hipStream_t stream) {
    (void)in_sizes; (void)n_in; (void)out_size;
    const float* x      = (const float*)d_in[0];
    const float* ln1_s  = (const float*)d_in[1];
    const float* ln1_b  = (const float*)d_in[2];
    const float* W_in   = (const float*)d_in[3];
    const float* b_in   = (const float*)d_in[4];
    const float* W_gate = (const float*)d_in[5];
    const float* b_gate = (const float*)d_in[6];
    const float* a_dec  = (const float*)d_in[7];
    const float* b_rot  = (const float*)d_in[8];
    const float* W_out  = (const float*)d_in[9];
    const float* b_out  = (const float*)d_in[10];
    const float* gamma1 = (const float*)d_in[11];
    const float* ln2_s  = (const float*)d_in[12];
    const float* ln2_b  = (const float*)d_in[13];
    const float* W1     = (const float*)d_in[14];
    const float* b1     = (const float*)d_in[15];
    const float* W2     = (const float*)d_in[16];
    const float* b2     = (const float*)d_in[17];
    const float* gamma2 = (const float*)d_in[18];
    float* out = (float*)d_out;

    const size_t NC = (size_t)NROWS * CDIM;           // 4,816,896
    if (ws_size < 6 * NC * sizeof(float)) return;     // visible failure if ws too small

    float* ws   = (float*)d_ws;
    float* buf0 = ws;              // xn -> g -> xn2
    float* buf1 = ws + NC;         // u  -> x1
    float* hx   = ws + 2 * NC;     // hx; later h overlays [2NC, 6NC)
    float* hy   = ws + 3 * NC;
    float* h    = ws + 2 * NC;     // N x HIDD (4*NC)

    const int n4 = (int)(NC / 4);
    const int eb = (n4 + 255) / 256;
    const dim3 gC(CDIM / BN, NROWS / BM);    // (12, 98)
    const dim3 gH(HIDD / BN, NROWS / BM);    // (48, 98)

    // branch 1
    ln_kernel<<<NROWS, 256, 0, stream>>>(x, ln1_s, ln1_b, buf0);
    gemm_k<EPI_BIAS, false><<<gC, 256, 0, stream>>>(buf0, nullptr, W_in, b_in,
                                                    nullptr, nullptr, buf1, CDIM, CDIM);
    init_state<<<eb, 256, 0, stream>>>(buf1, hx, hy, n4);
    for (int t = 1; t < 8; ++t) {
        gemm_k<EPI_SIG, true><<<gC, 256, 0, stream>>>(hx, hy, W_gate, b_gate,
                                                      nullptr, nullptr, buf0, 2 * CDIM, CDIM);
        state_update<<<eb, 256, 0, stream>>>(buf0, buf1, hx, hy, a_dec, b_rot, n4);
    }
    // x1 = x + (hx @ W_out + b_out) * gamma1   -> buf1
    gemm_k<EPI_RES, false><<<gC, 256, 0, stream>>>(hx, nullptr, W_out, b_out,
                                                   gamma1, x, buf1, CDIM, CDIM);
    // branch 2
    ln_kernel<<<NROWS, 256, 0, stream>>>(buf1, ln2_s, ln2_b, buf0);
    gemm_k<EPI_GELU, false><<<gH, 256, 0, stream>>>(buf0, nullptr, W1, b1,
                                                    nullptr, nullptr, h, CDIM, HIDD);
    gemm_k<EPI_RES, false><<<gC, 256, 0, stream>>>(h, nullptr, W2, b2,
                                                   gamma2, buf1, out, HIDD, CDIM);
}

// Round 2
// 707.435 us; speedup vs baseline: 4.0816x; 4.0816x over previous
//
#include <hip/hip_runtime.h>
#include <math.h>

typedef __bf16 bf16x8 __attribute__((ext_vector_type(8)));
typedef float  f32x4  __attribute__((ext_vector_type(4)));

#define NROWS 6272
#define CDIM  768
#define HIDD  3072

#define EPI_BIAS 0
#define EPI_SIG  1
#define EPI_GELU 2
#define EPI_RES  3

__device__ __forceinline__ void gload16(const void* g, void* l) {
    __builtin_amdgcn_global_load_lds(
        (const __attribute__((address_space(1))) void*)(uintptr_t)g,
        (__attribute__((address_space(3))) void*)(uintptr_t)l,
        16, 0, 0);
}

// ---------------- weight transpose + cast: W (K x N fp32) -> WT (N x K bf16) ----------------
__global__ __launch_bounds__(256) void transpose_w(const float* __restrict__ W,
                                                   __bf16* __restrict__ WT,
                                                   int K, int N) {
    __shared__ float tile[32][33];
    const int tx = threadIdx.x, ty = threadIdx.y;
    const int kb = blockIdx.y * 32, nb = blockIdx.x * 32;
    #pragma unroll
    for (int r = 0; r < 4; ++r)
        tile[ty + r * 8][tx] = W[(size_t)(kb + ty + r * 8) * N + nb + tx];
    __syncthreads();
    #pragma unroll
    for (int r = 0; r < 4; ++r)
        WT[(size_t)(nb + ty + r * 8) * K + kb + tx] = (__bf16)tile[tx][ty + r * 8];
}

// ---------------- LayerNorm (fp32 in, bf16 out): one block per row of 768 ----------------
__global__ __launch_bounds__(256) void ln_kernel(const float* __restrict__ x,
                                                 const float* __restrict__ sc,
                                                 const float* __restrict__ bi,
                                                 __bf16* __restrict__ o) {
    const int row = blockIdx.x;
    const float* xr = x + (size_t)row * CDIM;
    __bf16* orow = o + (size_t)row * CDIM;
    const int t = threadIdx.x;

    float v0 = xr[t], v1 = xr[t + 256], v2 = xr[t + 512];
    float s = v0 + v1 + v2;

    __shared__ float sm[8];
    #pragma unroll
    for (int off = 32; off > 0; off >>= 1) s += __shfl_xor(s, off);
    const int wid = t >> 6, lane = t & 63;
    if (lane == 0) sm[wid] = s;
    __syncthreads();
    const float mu = (sm[0] + sm[1] + sm[2] + sm[3]) * (1.0f / 768.0f);

    const float d0 = v0 - mu, d1 = v1 - mu, d2 = v2 - mu;
    float s2 = d0 * d0 + d1 * d1 + d2 * d2;
    #pragma unroll
    for (int off = 32; off > 0; off >>= 1) s2 += __shfl_xor(s2, off);
    if (lane == 0) sm[4 + wid] = s2;
    __syncthreads();
    const float var = (sm[4] + sm[5] + sm[6] + sm[7]) * (1.0f / 768.0f);
    const float r = rsqrtf(var + 1e-6f);

    orow[t]       = (__bf16)(d0 * r * sc[t]       + bi[t]);
    orow[t + 256] = (__bf16)(d1 * r * sc[t + 256] + bi[t + 256]);
    orow[t + 512] = (__bf16)(d2 * r * sc[t + 512] + bi[t + 512]);
}

// ---------------- bf16 MFMA GEMM: out = epi(A @ BT^T + bias) ----------------
// A: M x K bf16 row-major (stride lda). BT: N x K bf16 row-major (dense, ldb=K).
// 128x128 tile, BK=32, 256 threads (4 waves, each a 64x64 sub-tile of 4x4 16x16 frags).
// Verified fragment maps: A/B lane l -> row/col=l&15, k0=(l>>4)*8 ; C/D col=l&15, row=(l>>4)*4+reg.
template <int EPI>
__global__ __launch_bounds__(256) void mm_bf16(const __bf16* __restrict__ A, int lda,
                                               const __bf16* __restrict__ BT,
                                               const float* __restrict__ bias,
                                               const float* __restrict__ gamma,
                                               const float* __restrict__ res, int ldr,
                                               void* __restrict__ outv, int ldo,
                                               int K) {
    __shared__ __bf16 As[128 * 32];
    __shared__ __bf16 Bs[128 * 32];

    const int t  = threadIdx.x;
    const int w  = t >> 6;
    const int l  = t & 63;
    const int m0 = blockIdx.y * 128;
    const int n0 = blockIdx.x * 128;
    const int wm = w >> 1, wn = w & 1;

    const int rsub = t >> 2;        // staged row 0..63 (per 64-row half)
    const int ke   = (t & 3) * 8;   // staged k element offset

    const int fr = l & 15;
    const int kq = (l >> 4) * 8;

    f32x4 acc[4][4];
    #pragma unroll
    for (int i = 0; i < 4; ++i)
        #pragma unroll
        for (int j = 0; j < 4; ++j)
            acc[i][j] = f32x4{0.f, 0.f, 0.f, 0.f};

    const __bf16* gA = A  + (size_t)(m0 + rsub) * lda + ke;
    const __bf16* gB = BT + (size_t)(n0 + rsub) * K   + ke;
    __bf16* lA = &As[w * 512];   // + hardware lane*16B
    __bf16* lB = &Bs[w * 512];

    for (int k0 = 0; k0 < K; k0 += 32) {
        __syncthreads();                       // all waves done reading prev tile
        gload16(gA + k0,                        lA);
        gload16(gA + (size_t)64 * lda + k0,     lA + 2048);
        gload16(gB + k0,                        lB);
        gload16(gB + (size_t)64 * K + k0,       lB + 2048);
        __syncthreads();                       // drains vmcnt(0): tile resident

        bf16x8 av[4], bv[4];
        #pragma unroll
        for (int i = 0; i < 4; ++i)
            av[i] = *(const bf16x8*)&As[(wm * 64 + i * 16 + fr) * 32 + kq];
        #pragma unroll
        for (int j = 0; j < 4; ++j)
            bv[j] = *(const bf16x8*)&Bs[(wn * 64 + j * 16 + fr) * 32 + kq];
        #pragma unroll
        for (int i = 0; i < 4; ++i)
            #pragma unroll
            for (int j = 0; j < 4; ++j)
                acc[i][j] = __builtin_amdgcn_mfma_f32_16x16x32_bf16(av[i], bv[j], acc[i][j], 0, 0, 0);
    }

    const int row0 = m0 + wm * 64;
    const int col0 = n0 + wn * 64;
    #pragma unroll
    for (int i = 0; i < 4; ++i) {
        #pragma unroll
        for (int j = 0; j < 4; ++j) {
            const int col = col0 + j * 16 + fr;
            const float bsv = bias[col];
            #pragma unroll
            for (int r = 0; r < 4; ++r) {
                const int row = row0 + i * 16 + (l >> 4) * 4 + r;
                float z = acc[i][j][r] + bsv;
                if (EPI == EPI_SIG) {
                    z = 1.0f / (1.0f + __expf(-z));
                } else if (EPI == EPI_GELU) {
                    const float z3 = z * z * z;
                    z = 0.5f * z * (1.0f + tanhf(0.7978845608028654f * (z + 0.044715f * z3)));
                }
                if (EPI == EPI_RES) {
                    const float zz = res[(size_t)row * ldr + col] + z * gamma[col];
                    ((float*)outv)[(size_t)row * ldo + col] = zz;
                } else {
                    ((__bf16*)outv)[(size_t)row * ldo + col] = (__bf16)z;
                }
            }
        }
    }
}

// ---------------- recurrence elementwise ----------------
// t=0 collapses to hx=u, hy=0. hxy: (NROWS,1536) bf16, hx=[:768], hy=[768:].
__global__ __launch_bounds__(256) void init_state(const __bf16* __restrict__ u,
                                                  __bf16* __restrict__ hxy) {
    const int i = blockIdx.x * 256 + threadIdx.x;   // over NC/8
    const int row = i / 96, c8 = i % 96;
    const bf16x8 uv = *(const bf16x8*)&u[(size_t)i * 8];
    *(bf16x8*)&hxy[(size_t)row * 1536 + c8 * 8] = uv;
    *(uint4*)&hxy[(size_t)row * 1536 + 768 + c8 * 8] = make_uint4(0u, 0u, 0u, 0u);
}

__global__ __launch_bounds__(256) void state_update(const __bf16* __restrict__ g,
                                                    const __bf16* __restrict__ u,
                                                    __bf16* __restrict__ hxy,
                                                    const float* __restrict__ ad,
                                                    const float* __restrict__ br) {
    const int i = blockIdx.x * 256 + threadIdx.x;   // over NC/8
    const int row = i / 96, c8 = i % 96;
    __bf16* px = &hxy[(size_t)row * 1536 + c8 * 8];
    __bf16* py = px + 768;
    const bf16x8 gv = *(const bf16x8*)&g[(size_t)i * 8];
    const bf16x8 uv = *(const bf16x8*)&u[(size_t)i * 8];
    const bf16x8 xv = *(const bf16x8*)px;
    const bf16x8 yv = *(const bf16x8*)py;
    bf16x8 nx, ny;
    #pragma unroll
    for (int e = 0; e < 8; ++e) {
        const float a = ad[c8 * 8 + e], b = br[c8 * 8 + e];
        const float gf = (float)gv[e], uf = (float)uv[e];
        const float xf = (float)xv[e], yf = (float)yv[e];
        nx[e] = (__bf16)(gf * (a * xf - b * yf) + uf);
        ny[e] = (__bf16)(gf * (b * xf + a * yf));
    }
    *(bf16x8*)px = nx;
    *(bf16x8*)py = ny;
}

extern "C" void kernel_launch(void* const* d_in, const int* in_sizes, int n_in,
                              void* d_out, int out_size, void* d_ws, size_t ws_size,
                              hipStream_t stream) {
    (void)in_sizes; (void)n_in; (void)out_size;
    const float* x      = (const float*)d_in[0];
    const float* ln1_s  = (const float*)d_in[1];
    const float* ln1_b  = (const float*)d_in[2];
    const float* W_in   = (const float*)d_in[3];
    const float* b_in   = (const float*)d_in[4];
    const float* W_gate = (const float*)d_in[5];
    const float* b_gate = (const float*)d_in[6];
    const float* a_dec  = (const float*)d_in[7];
    const float* b_rot  = (const float*)d_in[8];
    const float* W_out  = (const float*)d_in[9];
    const float* b_out  = (const float*)d_in[10];
    const float* gamma1 = (const float*)d_in[11];
    const float* ln2_s  = (const float*)d_in[12];
    const float* ln2_b  = (const float*)d_in[13];
    const float* W1     = (const float*)d_in[14];
    const float* b1     = (const float*)d_in[15];
    const float* W2     = (const float*)d_in[16];
    const float* b2     = (const float*)d_in[17];
    const float* gamma2 = (const float*)d_in[18];
    float* out = (float*)d_out;

    // ---- workspace layout (bytes) ----
    if (ws_size < 81600000) return;
    char* w8 = (char*)d_ws;
    __bf16* WT_in   = (__bf16*)(w8);                       // 768x768   : 1,179,648
    __bf16* WT_gate = (__bf16*)(w8 + 1179648);             // 768x1536  : 2,359,296
    __bf16* WT_out  = (__bf16*)(w8 + 3538944);             // 768x768   : 1,179,648
    __bf16* WT1     = (__bf16*)(w8 + 4718592);             // 3072x768  : 4,718,592
    __bf16* WT2     = (__bf16*)(w8 + 9437184);             // 768x3072  : 4,718,592
    float*  x1      = (float*)(w8 + 14155776);             // NC fp32   : 19,267,584
    char*   pool    = w8 + 33423360;                       // 48,168,960-byte pool
    __bf16* xn  = (__bf16*)(pool);                         // NC bf16
    __bf16* u   = (__bf16*)(pool + 9633792);               // NC bf16
    __bf16* g   = (__bf16*)(pool + 19267584);              // NC bf16
    __bf16* hxy = (__bf16*)(pool + 28901376);              // 2*NC bf16
    __bf16* xn2 = (__bf16*)(pool);                         // branch-2 overlay
    __bf16* h   = (__bf16*)(pool + 9633792);               // NROWS*3072 bf16

    const dim3 tb(32, 8);
    transpose_w<<<dim3(24, 24), tb, 0, stream>>>(W_in,   WT_in,   768,  768);
    transpose_w<<<dim3(24, 48), tb, 0, stream>>>(W_gate, WT_gate, 1536, 768);
    transpose_w<<<dim3(24, 24), tb, 0, stream>>>(W_out,  WT_out,  768,  768);
    transpose_w<<<dim3(96, 24), tb, 0, stream>>>(W1,     WT1,     768,  3072);
    transpose_w<<<dim3(24, 96), tb, 0, stream>>>(W2,     WT2,     3072, 768);

    const dim3 gC(6, 49), gH(24, 49);
    const int eb = 2352;   // NC/8/256

    // branch 1
    ln_kernel<<<NROWS, 256, 0, stream>>>(x, ln1_s, ln1_b, xn);
    mm_bf16<EPI_BIAS><<<gC, 256, 0, stream>>>(xn, 768, WT_in, b_in,
                                              nullptr, nullptr, 0, u, 768, 768);
    init_state<<<eb, 256, 0, stream>>>(u, hxy);
    for (int ts = 1; ts < 8; ++ts) {
        mm_bf16<EPI_SIG><<<gC, 256, 0, stream>>>(hxy, 1536, WT_gate, b_gate,
                                                 nullptr, nullptr, 0, g, 768, 1536);
        state_update<<<eb, 256, 0, stream>>>(g, u, hxy, a_dec, b_rot);
    }
    mm_bf16<EPI_RES><<<gC, 256, 0, stream>>>(hxy, 1536, WT_out, b_out,
                                             gamma1, x, 768, x1, 768, 768);
    // branch 2
    ln_kernel<<<NROWS, 256, 0, stream>>>(x1, ln2_s, ln2_b, xn2);
    mm_bf16<EPI_GELU><<<gH, 256, 0, stream>>>(xn2, 768, WT1, b1,
                                              nullptr, nullptr, 0, h, 3072, 768);
    mm_bf16<EPI_RES><<<gC, 256, 0, stream>>>(h, 3072, WT2, b2,
                                             gamma2, x1, 768, out, 768, 3072);
}

// Round 3
// 615.694 us; speedup vs baseline: 4.6898x; 1.1490x over previous
//
#include <hip/hip_runtime.h>
#include <math.h>

typedef __bf16 bf16x8 __attribute__((ext_vector_type(8)));
typedef float  f32x4  __attribute__((ext_vector_type(4)));

#define NROWS 6272
#define CDIM  768
#define HIDD  3072

#define EPI_UINIT 0
#define EPI_GELU  2
#define EPI_RES   3

__device__ __forceinline__ void gload16(const void* g, void* l) {
    __builtin_amdgcn_global_load_lds(
        (const __attribute__((address_space(1))) void*)(uintptr_t)g,
        (__attribute__((address_space(3))) void*)(uintptr_t)l,
        16, 0, 0);
}

// m204 bijective XCD-chunked swizzle: consecutive wgid -> same XCD, so the
// n-blocks sharing an A row-panel hit one XCD's L2 (kills the 6x A re-fetch).
__device__ __forceinline__ void xcd_swz(int& m, int& n) {
    const int gx = gridDim.x;
    const int nwg = gx * gridDim.y;
    const int orig = blockIdx.x + gx * blockIdx.y;
    const int q = nwg >> 3, r = nwg & 7;
    const int xcd = orig & 7, loc = orig >> 3;
    const int wg = (xcd < r ? xcd * (q + 1) : r * (q + 1) + (xcd - r) * q) + loc;
    m = wg / gx;
    n = wg % gx;
}

// ---- shared GEMM core: 128x128 tile, BK=32, 4 waves, verified m97 fragment maps ----
// As/Bs layout: row-major [128][32] bf16. Wave w stages rows 16w..16w+15 per 64-half.
__device__ __forceinline__ void gemm_core(const __bf16* __restrict__ A, int lda,
                                          const __bf16* __restrict__ BT, int K,
                                          int m0, int n0,
                                          __bf16* As, __bf16* Bs,
                                          f32x4 acc[4][4]) {
    const int t  = threadIdx.x;
    const int w  = t >> 6;
    const int l  = t & 63;
    const int wm = w >> 1, wn = w & 1;
    const int rsub = t >> 2;
    const int ke   = (t & 3) * 8;
    const int fr = l & 15;
    const int kq = (l >> 4) * 8;

    const __bf16* gA = A  + (size_t)(m0 + rsub) * lda + ke;
    const __bf16* gB = BT + (size_t)(n0 + rsub) * K   + ke;
    __bf16* lA = &As[w * 512];
    __bf16* lB = &Bs[w * 512];

    for (int k0 = 0; k0 < K; k0 += 32) {
        __syncthreads();
        gload16(gA + k0,                    lA);
        gload16(gA + (size_t)64 * lda + k0, lA + 2048);
        gload16(gB + k0,                    lB);
        gload16(gB + (size_t)64 * K + k0,   lB + 2048);
        __syncthreads();

        bf16x8 av[4], bv[4];
        #pragma unroll
        for (int i = 0; i < 4; ++i)
            av[i] = *(const bf16x8*)&As[(wm * 64 + i * 16 + fr) * 32 + kq];
        #pragma unroll
        for (int j = 0; j < 4; ++j)
            bv[j] = *(const bf16x8*)&Bs[(wn * 64 + j * 16 + fr) * 32 + kq];
        #pragma unroll
        for (int i = 0; i < 4; ++i)
            #pragma unroll
            for (int j = 0; j < 4; ++j)
                acc[i][j] = __builtin_amdgcn_mfma_f32_16x16x32_bf16(av[i], bv[j], acc[i][j], 0, 0, 0);
    }
}

// ---------------- weight transpose + cast: W (K x N fp32) -> WT (N x K bf16) ----------------
__global__ __launch_bounds__(256) void transpose_w(const float* __restrict__ W,
                                                   __bf16* __restrict__ WT,
                                                   int K, int N) {
    __shared__ float tile[32][33];
    const int tx = threadIdx.x, ty = threadIdx.y;
    const int kb = blockIdx.y * 32, nb = blockIdx.x * 32;
    #pragma unroll
    for (int r = 0; r < 4; ++r)
        tile[ty + r * 8][tx] = W[(size_t)(kb + ty + r * 8) * N + nb + tx];
    __syncthreads();
    #pragma unroll
    for (int r = 0; r < 4; ++r)
        WT[(size_t)(nb + ty + r * 8) * K + kb + tx] = (__bf16)tile[tx][ty + r * 8];
}

// ---------------- LayerNorm (fp32 in, bf16 out) ----------------
__global__ __launch_bounds__(256) void ln_kernel(const float* __restrict__ x,
                                                 const float* __restrict__ sc,
                                                 const float* __restrict__ bi,
                                                 __bf16* __restrict__ o) {
    const int row = blockIdx.x;
    const float* xr = x + (size_t)row * CDIM;
    __bf16* orow = o + (size_t)row * CDIM;
    const int t = threadIdx.x;

    float v0 = xr[t], v1 = xr[t + 256], v2 = xr[t + 512];
    float s = v0 + v1 + v2;

    __shared__ float sm[8];
    #pragma unroll
    for (int off = 32; off > 0; off >>= 1) s += __shfl_xor(s, off);
    const int wid = t >> 6, lane = t & 63;
    if (lane == 0) sm[wid] = s;
    __syncthreads();
    const float mu = (sm[0] + sm[1] + sm[2] + sm[3]) * (1.0f / 768.0f);

    const float d0 = v0 - mu, d1 = v1 - mu, d2 = v2 - mu;
    float s2 = d0 * d0 + d1 * d1 + d2 * d2;
    #pragma unroll
    for (int off = 32; off > 0; off >>= 1) s2 += __shfl_xor(s2, off);
    if (lane == 0) sm[4 + wid] = s2;
    __syncthreads();
    const float var = (sm[4] + sm[5] + sm[6] + sm[7]) * (1.0f / 768.0f);
    const float r = rsqrtf(var + 1e-6f);

    orow[t]       = (__bf16)(d0 * r * sc[t]       + bi[t]);
    orow[t + 256] = (__bf16)(d1 * r * sc[t + 256] + bi[t + 256]);
    orow[t + 512] = (__bf16)(d2 * r * sc[t + 512] + bi[t + 512]);
}

// ---------------- generic GEMM with epilogues ----------------
// EPI_UINIT: out(bf16,ldo)=z, hxy0 hx=z, hy=0   (fused init_state)
// EPI_GELU : out(bf16,ldo)=gelu(z)
// EPI_RES  : out(f32,ldo)=res + z*gamma
template <int EPI>
__global__ __launch_bounds__(256) void mm_bf16(const __bf16* __restrict__ A, int lda,
                                               const __bf16* __restrict__ BT,
                                               const float* __restrict__ bias,
                                               const float* __restrict__ gamma,
                                               const float* __restrict__ res, int ldr,
                                               void* __restrict__ outv, int ldo,
                                               int K, __bf16* __restrict__ hxy0) {
    __shared__ __bf16 As[128 * 32];
    __shared__ __bf16 Bs[128 * 32];
    int mb, nb;
    xcd_swz(mb, nb);
    const int m0 = mb * 128, n0 = nb * 128;

    f32x4 acc[4][4];
    #pragma unroll
    for (int i = 0; i < 4; ++i)
        #pragma unroll
        for (int j = 0; j < 4; ++j)
            acc[i][j] = f32x4{0.f, 0.f, 0.f, 0.f};

    gemm_core(A, lda, BT, K, m0, n0, As, Bs, acc);

    const int l = threadIdx.x & 63;
    const int w = threadIdx.x >> 6;
    const int wm = w >> 1, wn = w & 1;
    const int fr = l & 15;
    const int row0 = m0 + wm * 64;
    const int col0 = n0 + wn * 64;
    #pragma unroll
    for (int i = 0; i < 4; ++i) {
        #pragma unroll
        for (int j = 0; j < 4; ++j) {
            const int col = col0 + j * 16 + fr;
            const float bsv = bias[col];
            #pragma unroll
            for (int r = 0; r < 4; ++r) {
                const int row = row0 + i * 16 + (l >> 4) * 4 + r;
                float z = acc[i][j][r] + bsv;
                if (EPI == EPI_UINIT) {
                    ((__bf16*)outv)[(size_t)row * ldo + col] = (__bf16)z;
                    hxy0[(size_t)row * 1536 + col] = (__bf16)z;
                    hxy0[(size_t)row * 1536 + 768 + col] = (__bf16)0.f;
                } else if (EPI == EPI_GELU) {
                    const float z3 = z * z * z;
                    z = 0.5f * z * (1.0f + tanhf(0.7978845608028654f * (z + 0.044715f * z3)));
                    ((__bf16*)outv)[(size_t)row * ldo + col] = (__bf16)z;
                } else {  // EPI_RES
                    const float zz = res[(size_t)row * ldr + col] + z * gamma[col];
                    ((float*)outv)[(size_t)row * ldo + col] = zz;
                }
            }
        }
    }
}

// ---------------- fused gate GEMM + sigmoid + opponent state update ----------------
// Reads hxy_cur (A, lda=1536, K=1536), writes hxy_next (ping-pong: no cross-block race).
template <bool LAST>
__global__ __launch_bounds__(256) void gate_step(const __bf16* __restrict__ hxy_cur,
                                                 const __bf16* __restrict__ WT_gate,
                                                 const float* __restrict__ b_gate,
                                                 const __bf16* __restrict__ u,
                                                 const float* __restrict__ ad,
                                                 const float* __restrict__ br,
                                                 __bf16* __restrict__ hxy_next) {
    __shared__ __bf16 As[128 * 32];
    __shared__ __bf16 Bs[128 * 32];
    int mb, nb;
    xcd_swz(mb, nb);
    const int m0 = mb * 128, n0 = nb * 128;

    f32x4 acc[4][4];
    #pragma unroll
    for (int i = 0; i < 4; ++i)
        #pragma unroll
        for (int j = 0; j < 4; ++j)
            acc[i][j] = f32x4{0.f, 0.f, 0.f, 0.f};

    gemm_core(hxy_cur, 1536, WT_gate, 1536, m0, n0, As, Bs, acc);

    const int l = threadIdx.x & 63;
    const int w = threadIdx.x >> 6;
    const int wm = w >> 1, wn = w & 1;
    const int fr = l & 15;
    const int row0 = m0 + wm * 64;
    const int col0 = n0 + wn * 64;
    #pragma unroll
    for (int i = 0; i < 4; ++i) {
        #pragma unroll
        for (int j = 0; j < 4; ++j) {
            const int col = col0 + j * 16 + fr;
            const float bg = b_gate[col];
            const float av = ad[col];
            const float bv = br[col];
            #pragma unroll
            for (int r = 0; r < 4; ++r) {
                const int row = row0 + i * 16 + (l >> 4) * 4 + r;
                float z = acc[i][j][r] + bg;
                z = 1.0f / (1.0f + __expf(-z));
                const size_t base = (size_t)row * 1536 + col;
                const float hx = (float)hxy_cur[base];
                const float hy = (float)hxy_cur[base + 768];
                const float uf = (float)u[(size_t)row * 768 + col];
                hxy_next[base] = (__bf16)(z * (av * hx - bv * hy) + uf);
                if (!LAST)
                    hxy_next[base + 768] = (__bf16)(z * (bv * hx + av * hy));
            }
        }
    }
}

extern "C" void kernel_launch(void* const* d_in, const int* in_sizes, int n_in,
                              void* d_out, int out_size, void* d_ws, size_t ws_size,
                              hipStream_t stream) {
    (void)in_sizes; (void)n_in; (void)out_size;
    const float* x      = (const float*)d_in[0];
    const float* ln1_s  = (const float*)d_in[1];
    const float* ln1_b  = (const float*)d_in[2];
    const float* W_in   = (const float*)d_in[3];
    const float* b_in   = (const float*)d_in[4];
    const float* W_gate = (const float*)d_in[5];
    const float* b_gate = (const float*)d_in[6];
    const float* a_dec  = (const float*)d_in[7];
    const float* b_rot  = (const float*)d_in[8];
    const float* W_out  = (const float*)d_in[9];
    const float* b_out  = (const float*)d_in[10];
    const float* gamma1 = (const float*)d_in[11];
    const float* ln2_s  = (const float*)d_in[12];
    const float* ln2_b  = (const float*)d_in[13];
    const float* W1     = (const float*)d_in[14];
    const float* b1     = (const float*)d_in[15];
    const float* W2     = (const float*)d_in[16];
    const float* b2     = (const float*)d_in[17];
    const float* gamma2 = (const float*)d_in[18];
    float* out = (float*)d_out;

    // ---- workspace layout (bytes); round-1 proved ws_size >= 115.6 MB ----
    if (ws_size < 92000000) return;
    char* w8 = (char*)d_ws;
    __bf16* WT_in   = (__bf16*)(w8);                 // 768x768  bf16
    __bf16* WT_gate = (__bf16*)(w8 + 1179648);       // 768x1536 bf16
    __bf16* WT_out  = (__bf16*)(w8 + 3538944);       // 768x768  bf16
    __bf16* WT1     = (__bf16*)(w8 + 4718592);       // 3072x768 bf16
    __bf16* WT2     = (__bf16*)(w8 + 9437184);       // 768x3072 bf16
    float*  x1      = (float*)(w8 + 14155776);       // NC fp32
    __bf16* xn      = (__bf16*)(w8 + 33423360);      // NC bf16 (xn2 overlay)
    __bf16* u       = (__bf16*)(w8 + 43057152);      // NC bf16
    __bf16* hxy_a   = (__bf16*)(w8 + 52690944);      // NROWSx1536 bf16
    __bf16* hxy_b   = (__bf16*)(w8 + 71958528);      // NROWSx1536 bf16
    __bf16* h       = (__bf16*)(w8 + 52690944);      // NROWSx3072 bf16 (overlays hxy_a+b, dead by then)

    const dim3 tb(32, 8);
    transpose_w<<<dim3(24, 24), tb, 0, stream>>>(W_in,   WT_in,   768,  768);
    transpose_w<<<dim3(24, 48), tb, 0, stream>>>(W_gate, WT_gate, 1536, 768);
    transpose_w<<<dim3(24, 24), tb, 0, stream>>>(W_out,  WT_out,  768,  768);
    transpose_w<<<dim3(96, 24), tb, 0, stream>>>(W1,     WT1,     768,  3072);
    transpose_w<<<dim3(24, 96), tb, 0, stream>>>(W2,     WT2,     3072, 768);

    const dim3 gC(6, 49), gH(24, 49);

    // branch 1
    ln_kernel<<<NROWS, 256, 0, stream>>>(x, ln1_s, ln1_b, xn);
    // u = xn@W_in + b ; hx0 = u ; hy0 = 0  (t=0 step collapsed)
    mm_bf16<EPI_UINIT><<<gC, 256, 0, stream>>>(xn, 768, WT_in, b_in,
                                               nullptr, nullptr, 0, u, 768, 768, hxy_a);
    __bf16* cur = hxy_a;
    __bf16* nxt = hxy_b;
    for (int ts = 1; ts < 8; ++ts) {
        if (ts == 7)
            gate_step<true><<<gC, 256, 0, stream>>>(cur, WT_gate, b_gate, u, a_dec, b_rot, nxt);
        else
            gate_step<false><<<gC, 256, 0, stream>>>(cur, WT_gate, b_gate, u, a_dec, b_rot, nxt);
        __bf16* tmp = cur; cur = nxt; nxt = tmp;
    }
    // x1 = x + (hx @ W_out + b_out) * gamma1   (hx = first 768 cols of cur, lda 1536)
    mm_bf16<EPI_RES><<<gC, 256, 0, stream>>>(cur, 1536, WT_out, b_out,
                                             gamma1, x, 768, x1, 768, 768, nullptr);
    // branch 2
    ln_kernel<<<NROWS, 256, 0, stream>>>(x1, ln2_s, ln2_b, xn);
    mm_bf16<EPI_GELU><<<gH, 256, 0, stream>>>(xn, 768, WT1, b1,
                                              nullptr, nullptr, 0, h, 3072, 768, nullptr);
    mm_bf16<EPI_RES><<<gC, 256, 0, stream>>>(h, 3072, WT2, b2,
                                             gamma2, x1, 768, out, 768, 3072, nullptr);
}